// Round 18
// baseline (109.980 us; speedup 1.0000x reference)
//
#include <hip/hip_runtime.h>
#include <math.h>

#define B_ 8
#define N_ 2048
#define H_ 256

typedef double d4 __attribute__((ext_vector_type(4)));

// One-shot: W1T[k][o] = W1[o][k] (f32) -> for the VALU fallback only.
__global__ __launch_bounds__(256)
void transpose_w1(const float* __restrict__ W1, float* __restrict__ W1T) {
    W1T[(size_t)blockIdx.x * H_ + threadIdx.x] =
        W1[(size_t)threadIdx.x * H_ + blockIdx.x];
}

// One-shot: pack B for the MFMA path. W1P[o][(k&3)*64 + (k>>2)] = W1[o][k],
// so lane (g) of an mfma B-fragment reads k = {16c+g, 16c+4+g, 16c+8+g,
// 16c+12+g} as ONE float4 at W1P + (o*4+g)*64 + c*4. Both sides coalesced
// (permutation stays inside each 1KB o-row).
__global__ __launch_bounds__(256)
void pack_w1(const float* __restrict__ W1, float* __restrict__ W1P) {
    const int o = blockIdx.x, k = threadIdx.x;
    W1P[(size_t)o * H_ + (k & 3) * 64 + (k >> 2)] = W1[(size_t)o * H_ + k];
}

// In-kernel probe of the v_mfma_f64_16x16x4_f64 lane mapping (~200 cy).
// Round 15/16 proved one of vars 1-4 matches on this chip.
__device__ __forceinline__ int self_probe_var() {
    const int l = threadIdx.x & 63;
    d4 z = {0.0, 0.0, 0.0, 0.0};
    d4 r1 = __builtin_amdgcn_mfma_f64_16x16x4f64((double)(l + 1), 1.0, z, 0, 0, 0);
    d4 r2 = __builtin_amdgcn_mfma_f64_16x16x4f64(1.0, (double)(l + 1), z, 0, 0, 0);
    d4 r3 = __builtin_amdgcn_mfma_f64_16x16x4f64((double)(l & 15), 1.0, z, 0, 0, 0);
    const double pw0 = __shfl(r1[0], 0, 64);
    const double pw1 = __shfl(r2[0], 0, 64);
    const double pw2 = __shfl(r3[0], 1, 64);
    const double pw3 = __shfl(r3[2], 16, 64);
    const double pw4 = __shfl(r2[2], 16, 64);
    if (pw0 != 100.0 || pw1 != 100.0) return 0;
    if (pw2 == 0.0 && pw3 == 24.0)  return 1;   // row=4g+v, col=a15
    if (pw2 == 0.0 && pw3 == 36.0)  return 3;   // row=g+4v, col=a15
    if (pw2 == 4.0 && pw4 == 124.0) return 2;   // row=a15,  col=4g+v
    if (pw2 == 4.0 && pw4 == 136.0) return 4;   // row=a15,  col=g+4v
    return 0;
}

// MFMA s-kernel. 16 rows/block, grid 1024 = 4 blocks/CU = 4 waves/SIMD
// (occupancy 2x round 17). Wave = 4 o-tiles (64-o strip). Inner loop
// (16 k per iter): 16 mfma vs 8 loads (4 B float4 via W1P + 4 A scalars),
// prefetched one iteration ahead. acc = 32 VGPR; ~96 total.
__global__ __launch_bounds__(256)
__attribute__((amdgpu_waves_per_eu(2, 4)))
void s_mfma_uni(const float* __restrict__ hp, const float* __restrict__ W1P,
                const float* __restrict__ b1, const float* __restrict__ w2,
                double* __restrict__ s_out) {
    const int var = self_probe_var();
    if (var == 0) return;                       // VALU fallback does the work
    __shared__ double spart[4][16];
    const int t = threadIdx.x;
    const int lane = t & 63;
    const int wave = __builtin_amdgcn_readfirstlane(t >> 6);
    const int a15 = lane & 15, g = lane >> 4;
    const int m0 = blockIdx.x * 16;
    const int oc = wave * 64;
    const float* ap = hp + (size_t)(m0 + a15) * H_ + g;   // A: h[m0+a15][16c+4q+g]
    const float* bq0 = W1P + ((size_t)(oc + 0 * 16 + a15) * 4 + g) * 64;
    const float* bq1 = W1P + ((size_t)(oc + 1 * 16 + a15) * 4 + g) * 64;
    const float* bq2 = W1P + ((size_t)(oc + 2 * 16 + a15) * 4 + g) * 64;
    const float* bq3 = W1P + ((size_t)(oc + 3 * 16 + a15) * 4 + g) * 64;

    d4 acc[4];
    #pragma unroll
    for (int ot = 0; ot < 4; ++ot) acc[ot] = (d4){0.0, 0.0, 0.0, 0.0};

    float bc[16], bn[16];      // B chunk: [ot*4 + q]
    float ac[4], an[4];        // A chunk: [q], k = 16c + 4q + g

    #define LOADB(dst, c)                                                     \
        do {                                                                  \
            float4 f0 = *reinterpret_cast<const float4*>(bq0 + (c) * 4);      \
            float4 f1 = *reinterpret_cast<const float4*>(bq1 + (c) * 4);      \
            float4 f2 = *reinterpret_cast<const float4*>(bq2 + (c) * 4);      \
            float4 f3 = *reinterpret_cast<const float4*>(bq3 + (c) * 4);      \
            dst[0]=f0.x;  dst[1]=f0.y;  dst[2]=f0.z;  dst[3]=f0.w;            \
            dst[4]=f1.x;  dst[5]=f1.y;  dst[6]=f1.z;  dst[7]=f1.w;            \
            dst[8]=f2.x;  dst[9]=f2.y;  dst[10]=f2.z; dst[11]=f2.w;           \
            dst[12]=f3.x; dst[13]=f3.y; dst[14]=f3.z; dst[15]=f3.w;           \
        } while (0)

    #define LOADA(dst, c)                                                     \
        do {                                                                  \
            _Pragma("unroll")                                                 \
            for (int q = 0; q < 4; ++q) dst[q] = ap[(c) * 16 + q * 4];        \
        } while (0)

    LOADB(bc, 0);
    LOADA(ac, 0);
    for (int c = 0; c < 16; ++c) {
        const int cn = (c + 1 < 16) ? (c + 1) : 0;        // guarded prefetch
        LOADB(bn, cn);
        LOADA(an, cn);
        #pragma unroll
        for (int q = 0; q < 4; ++q) {
            const double av = (double)ac[q];
            acc[0] = __builtin_amdgcn_mfma_f64_16x16x4f64(av, (double)bc[0 * 4 + q], acc[0], 0, 0, 0);
            acc[1] = __builtin_amdgcn_mfma_f64_16x16x4f64(av, (double)bc[1 * 4 + q], acc[1], 0, 0, 0);
            acc[2] = __builtin_amdgcn_mfma_f64_16x16x4f64(av, (double)bc[2 * 4 + q], acc[2], 0, 0, 0);
            acc[3] = __builtin_amdgcn_mfma_f64_16x16x4f64(av, (double)bc[3 * 4 + q], acc[3], 0, 0, 0);
        }
        #pragma unroll
        for (int q = 0; q < 4; ++q) ac[q] = an[q];
        #pragma unroll
        for (int q = 0; q < 16; ++q) bc[q] = bn[q];
    }
    #undef LOADB
    #undef LOADA

    if (var == 1 || var == 3) {
        // col = a15 (fixed per lane); row = 4g+v (var 1) or g+4v (var 3).
        double psum[4] = {0.0, 0.0, 0.0, 0.0};
        #pragma unroll
        for (int ot = 0; ot < 4; ++ot) {
            const int o = oc + ot * 16 + a15;
            const double bb = (double)b1[o];
            const double ww = (double)w2[o];
            #pragma unroll
            for (int v = 0; v < 4; ++v) {
                const double u = acc[ot][v] + bb;
                psum[v] += ww * (u / (1.0 + exp(-u)));
            }
        }
        #pragma unroll
        for (int v = 0; v < 4; ++v) {
            double x = psum[v];
            x += __shfl_xor(x, 1, 64);
            x += __shfl_xor(x, 2, 64);
            x += __shfl_xor(x, 4, 64);
            x += __shfl_xor(x, 8, 64);
            psum[v] = x;
        }
        if (a15 == 0) {
            #pragma unroll
            for (int v = 0; v < 4; ++v) {
                const int row = (var == 1) ? (4 * g + v) : (g + 4 * v);
                spart[wave][row] = psum[v];
            }
        }
    } else {
        // row = a15 (fixed per lane); col = 4g+v (var 2) or g+4v (var 4).
        double ps = 0.0;
        #pragma unroll
        for (int ot = 0; ot < 4; ++ot)
            #pragma unroll
            for (int v = 0; v < 4; ++v) {
                const int cv = (var == 2) ? (4 * g + v) : (g + 4 * v);
                const int o = oc + ot * 16 + cv;
                const double u = acc[ot][v] + (double)b1[o];
                ps += (double)w2[o] * (u / (1.0 + exp(-u)));
            }
        ps += __shfl_xor(ps, 16, 64);
        ps += __shfl_xor(ps, 32, 64);
        if (g == 0) spart[wave][a15] = ps;
    }
    __syncthreads();
    if (t < 16)
        s_out[m0 + t] = spart[0][t] + spart[1][t] + spart[2][t] + spart[3][t];
}

// VALU fallback (round-11 verified body, W1T layout): only if probe var==0.
__global__ __launch_bounds__(256)
__attribute__((amdgpu_waves_per_eu(2, 4)))
void s_valu_kernel(const float* __restrict__ hp, const float* __restrict__ W1T,
                   const float* __restrict__ b1, const float* __restrict__ w2,
                   double* __restrict__ s_out) {
    if (self_probe_var() != 0) return;
    const int t = threadIdx.x;
    const int lane = t & 63;
    const int wave = __builtin_amdgcn_readfirstlane(t >> 6);
    const int m0 = blockIdx.x * 16 + wave * 4;
    const int o0 = lane * 4;
    const float* hr = hp + (size_t)m0 * H_;
    const float* wp = W1T + o0;

    double acc[4][4];
    #pragma unroll
    for (int j = 0; j < 4; ++j)
        #pragma unroll
        for (int r = 0; r < 4; ++r) acc[j][r] = 0.0;

    float4 wA[8], wB[8];
    float hA[32], hB[32];

    #define LOADW(dst, kcv)                                                   \
        do {                                                                  \
            _Pragma("unroll")                                                 \
            for (int kk = 0; kk < 8; ++kk)                                    \
                dst[kk] = *reinterpret_cast<const float4*>(                   \
                    wp + (size_t)((kcv) + kk) * H_);                          \
        } while (0)

    #define LOADH(dst, kcv)                                                   \
        do {                                                                  \
            _Pragma("unroll")                                                 \
            for (int r = 0; r < 4; ++r)                                       \
                _Pragma("unroll")                                             \
                for (int kk = 0; kk < 8; ++kk)                                \
                    dst[r * 8 + kk] = hr[r * H_ + (kcv) + kk];                \
        } while (0)

    #define COMPUTE(wv, hbuf)                                                 \
        do {                                                                  \
            _Pragma("unroll")                                                 \
            for (int kk = 0; kk < 8; ++kk) {                                  \
                const double h0 = (double)hbuf[0 * 8 + kk];                   \
                const double h1 = (double)hbuf[1 * 8 + kk];                   \
                const double h2 = (double)hbuf[2 * 8 + kk];                   \
                const double h3 = (double)hbuf[3 * 8 + kk];                   \
                const double a0 = (double)wv[kk].x;                           \
                const double a1 = (double)wv[kk].y;                           \
                const double a2 = (double)wv[kk].z;                           \
                const double a3 = (double)wv[kk].w;                           \
                acc[0][0] = fma(a0, h0, acc[0][0]);                           \
                acc[0][1] = fma(a0, h1, acc[0][1]);                           \
                acc[0][2] = fma(a0, h2, acc[0][2]);                           \
                acc[0][3] = fma(a0, h3, acc[0][3]);                           \
                acc[1][0] = fma(a1, h0, acc[1][0]);                           \
                acc[1][1] = fma(a1, h1, acc[1][1]);                           \
                acc[1][2] = fma(a1, h2, acc[1][2]);                           \
                acc[1][3] = fma(a1, h3, acc[1][3]);                           \
                acc[2][0] = fma(a2, h0, acc[2][0]);                           \
                acc[2][1] = fma(a2, h1, acc[2][1]);                           \
                acc[2][2] = fma(a2, h2, acc[2][2]);                           \
                acc[2][3] = fma(a2, h3, acc[2][3]);                           \
                acc[3][0] = fma(a3, h0, acc[3][0]);                           \
                acc[3][1] = fma(a3, h1, acc[3][1]);                           \
                acc[3][2] = fma(a3, h2, acc[3][2]);                           \
                acc[3][3] = fma(a3, h3, acc[3][3]);                           \
            }                                                                 \
        } while (0)

    LOADW(wA, 0);
    LOADH(hA, 0);
    for (int kc = 0; kc < H_; kc += 16) {
        LOADW(wB, kc + 8);
        LOADH(hB, kc + 8);
        COMPUTE(wA, hA);
        if (kc + 16 < H_) {
            LOADW(wA, kc + 16);
            LOADH(hA, kc + 16);
        }
        COMPUTE(wB, hB);
    }
    #undef LOADW
    #undef LOADH
    #undef COMPUTE

    const float4 b1v = *reinterpret_cast<const float4*>(b1 + o0);
    const float4 w2v = *reinterpret_cast<const float4*>(w2 + o0);
    double psum[4] = {0.0, 0.0, 0.0, 0.0};
    #define EPI(j, bc, wc)                                                    \
        do {                                                                  \
            const double bb = (double)bc, ww = (double)wc;                    \
            _Pragma("unroll")                                                 \
            for (int r = 0; r < 4; ++r) {                                     \
                const double u = acc[j][r] + bb;                              \
                psum[r] += ww * (u / (1.0 + exp(-u)));                        \
            }                                                                 \
        } while (0)
    EPI(0, b1v.x, w2v.x);
    EPI(1, b1v.y, w2v.y);
    EPI(2, b1v.z, w2v.z);
    EPI(3, b1v.w, w2v.w);
    #undef EPI

    #pragma unroll
    for (int r = 0; r < 4; ++r) {
        double v = psum[r];
        v += __shfl_xor(v, 1, 64);
        v += __shfl_xor(v, 2, 64);
        v += __shfl_xor(v, 4, 64);
        v += __shfl_xor(v, 8, 64);
        v += __shfl_xor(v, 16, 64);
        v += __shfl_xor(v, 32, 64);
        if (lane == 0) s_out[m0 + r] = v;
    }
}

// Kernel B: out[b,i,j] = (int32)trunc( (s[b,i] - s[b,j]) + b2 )
__global__ __launch_bounds__(256)
void pair_kernel(const double* __restrict__ s, const float* __restrict__ b2p,
                 int* __restrict__ out) {
    const double b2 = (double)b2p[0];
    const unsigned total4 = (unsigned)(B_) * (unsigned)(N_) * (unsigned)(N_) / 4u;
    const unsigned stride = gridDim.x * blockDim.x;
    for (unsigned idx = blockIdx.x * blockDim.x + threadIdx.x; idx < total4;
         idx += stride) {
        const unsigned base = idx * 4u;                 // element index, %4==0
        const unsigned bi  = base >> 22;                // / (N*N), N*N = 2^22
        const unsigned rem = base & ((1u << 22) - 1u);
        const unsigned i   = rem >> 11;                 // / N
        const unsigned j   = rem & (N_ - 1u);
        const double si = s[bi * N_ + i];
        const double* sp = s + bi * N_ + j;             // 32B aligned (j%4==0)
        const double sj0 = sp[0], sj1 = sp[1], sj2 = sp[2], sj3 = sp[3];
        int4 o;
        o.x = (int)trunc((si - sj0) + b2);
        o.y = (int)trunc((si - sj1) + b2);
        o.z = (int)trunc((si - sj2) + b2);
        o.w = (int)trunc((si - sj3) + b2);
        *reinterpret_cast<int4*>(out + base) = o;
    }
}

extern "C" void kernel_launch(void* const* d_in, const int* in_sizes, int n_in,
                              void* d_out, int out_size, void* d_ws, size_t ws_size,
                              hipStream_t stream) {
    const float* hp = (const float*)d_in[0];
    // d_in[1] = node_mask (unused), d_in[2] = n_nodes (unused)
    const float* W1 = (const float*)d_in[3];
    const float* b1 = (const float*)d_in[4];
    const float* w2 = (const float*)d_in[5];
    const float* b2 = (const float*)d_in[6];

    float*  W1T = (float*)d_ws;                                   // 256 KB
    float*  W1P = (float*)((char*)d_ws + 256 * 1024);             // 256 KB
    double* s   = (double*)((char*)d_ws + 512 * 1024);            // 128 KB
    int* out = (int*)d_out;

    transpose_w1<<<H_, H_, 0, stream>>>(W1, W1T);
    pack_w1<<<H_, H_, 0, stream>>>(W1, W1P);
    s_mfma_uni<<<(B_ * N_) / 16, 256, 0, stream>>>(hp, W1P, b1, w2, s);
    s_valu_kernel<<<(B_ * N_) / 16, 256, 0, stream>>>(hp, W1T, b1, w2, s);
    pair_kernel<<<2048, 256, 0, stream>>>(s, b2, out);
}

// Round 19
// 89.489 us; speedup vs baseline: 1.2290x; 1.2290x over previous
//
#include <hip/hip_runtime.h>
#include <math.h>

#define B_ 8
#define N_ 2048
#define H_ 256

typedef double d4 __attribute__((ext_vector_type(4)));

// One-shot: W1T[k][o] = W1[o][k] (f32) -> for the VALU fallback only.
__global__ __launch_bounds__(256)
void transpose_w1(const float* __restrict__ W1, float* __restrict__ W1T) {
    W1T[(size_t)blockIdx.x * H_ + threadIdx.x] =
        W1[(size_t)threadIdx.x * H_ + blockIdx.x];
}

// One-shot: pack B for the MFMA path (verified in round 18, absmax 0).
// W1P[o][(k&3)*64 + (k>>2)] = W1[o][k]: lane g of a B-fragment reads
// k = {16c+g, 16c+4+g, 16c+8+g, 16c+12+g} as ONE float4 at
// W1P + (o*4+g)*64 + c*4.
__global__ __launch_bounds__(256)
void pack_w1(const float* __restrict__ W1, float* __restrict__ W1P) {
    const int o = blockIdx.x, k = threadIdx.x;
    W1P[(size_t)o * H_ + (k & 3) * 64 + (k >> 2)] = W1[(size_t)o * H_ + k];
}

// In-kernel probe of the v_mfma_f64_16x16x4_f64 lane mapping (~200 cy).
// Rounds 15-18 proved one of vars 1-4 matches on this chip.
__device__ __forceinline__ int self_probe_var() {
    const int l = threadIdx.x & 63;
    d4 z = {0.0, 0.0, 0.0, 0.0};
    d4 r1 = __builtin_amdgcn_mfma_f64_16x16x4f64((double)(l + 1), 1.0, z, 0, 0, 0);
    d4 r2 = __builtin_amdgcn_mfma_f64_16x16x4f64(1.0, (double)(l + 1), z, 0, 0, 0);
    d4 r3 = __builtin_amdgcn_mfma_f64_16x16x4f64((double)(l & 15), 1.0, z, 0, 0, 0);
    const double pw0 = __shfl(r1[0], 0, 64);
    const double pw1 = __shfl(r2[0], 0, 64);
    const double pw2 = __shfl(r3[0], 1, 64);
    const double pw3 = __shfl(r3[2], 16, 64);
    const double pw4 = __shfl(r2[2], 16, 64);
    if (pw0 != 100.0 || pw1 != 100.0) return 0;
    if (pw2 == 0.0 && pw3 == 24.0)  return 1;   // row=4g+v, col=a15
    if (pw2 == 0.0 && pw3 == 36.0)  return 3;   // row=g+4v, col=a15
    if (pw2 == 4.0 && pw4 == 124.0) return 2;   // row=a15,  col=4g+v
    if (pw2 == 4.0 && pw4 == 136.0) return 4;   // row=a15,  col=g+4v
    return 0;
}

// MFMA s-kernel, round-19 geometry: 32 rows/block (grid 512), 4 waves;
// wave = 2 m-tiles x 4 o-tiles = 8 independent acc chains. Inner loop
// (16 k per iter): 32 mfma (2048 cy of f64-pipe time at 64 cy/mfma, per
// round-18 measurement) vs 12 loads (4 B-float4 via W1P + 8 A scalars,
// B shared by both m-tiles), prefetched one iteration ahead.
// Round-18 lesson: mfma pipe runs at full 78.6 TF when fed (busy time
// matched the 27.3 us floor exactly); the job is keeping it fed.
__global__ __launch_bounds__(256)
__attribute__((amdgpu_waves_per_eu(2, 4)))
void s_mfma_uni(const float* __restrict__ hp, const float* __restrict__ W1P,
                const float* __restrict__ b1, const float* __restrict__ w2,
                double* __restrict__ s_out) {
    const int var = self_probe_var();
    if (var == 0) return;                       // VALU fallback does the work
    __shared__ double spart[4][32];
    const int t = threadIdx.x;
    const int lane = t & 63;
    const int wave = __builtin_amdgcn_readfirstlane(t >> 6);
    const int a15 = lane & 15, g = lane >> 4;
    const int m0 = blockIdx.x * 32;
    const int oc = wave * 64;
    // A: h[m0 + mt*16 + a15][16c + 4q + g]
    const float* ap0 = hp + (size_t)(m0 + a15) * H_ + g;
    const float* ap1 = ap0 + 16 * H_;
    // B: lane's float4 for (ot, chunk c) at bq + ot*4096 + c*4
    const float* bq = W1P + ((size_t)(oc + a15) * 4 + g) * 64;

    d4 acc[2][4];
    #pragma unroll
    for (int mt = 0; mt < 2; ++mt)
        #pragma unroll
        for (int ot = 0; ot < 4; ++ot) acc[mt][ot] = (d4){0.0, 0.0, 0.0, 0.0};

    float4 bc[4], bn[4];       // B chunk: [ot] -> (q in .x/.y/.z/.w)
    float ac[8], an[8];        // A chunk: [mt*4 + q], k = 16c + 4q + g

    #define LOADB(dst, c)                                                     \
        do {                                                                  \
            _Pragma("unroll")                                                 \
            for (int ot = 0; ot < 4; ++ot)                                    \
                dst[ot] = *reinterpret_cast<const float4*>(                   \
                    bq + ot * 16 * H_ * 4 / 4 * 4 / 4 + 0);                   \
        } while (0)
    #undef LOADB
    // (ot stride in floats: (ot*16)*H_ = ot*4096)
    #define LOADB(dst, c)                                                     \
        do {                                                                  \
            _Pragma("unroll")                                                 \
            for (int ot = 0; ot < 4; ++ot)                                    \
                dst[ot] = *reinterpret_cast<const float4*>(                   \
                    bq + (size_t)ot * 4096 + (c) * 4);                        \
        } while (0)

    #define LOADA(dst, c)                                                     \
        do {                                                                  \
            _Pragma("unroll")                                                 \
            for (int q = 0; q < 4; ++q) {                                     \
                dst[q]     = ap0[(c) * 16 + q * 4];                           \
                dst[4 + q] = ap1[(c) * 16 + q * 4];                           \
            }                                                                 \
        } while (0)

    LOADB(bc, 0);
    LOADA(ac, 0);
    for (int c = 0; c < 16; ++c) {
        const int cn = (c + 1 < 16) ? (c + 1) : 0;        // guarded prefetch
        LOADB(bn, cn);
        LOADA(an, cn);
        #pragma unroll
        for (int q = 0; q < 4; ++q) {
            const double a0 = (double)ac[q];
            const double a1 = (double)ac[4 + q];
            const double b0 = (double)((const float*)&bc[0])[q];
            const double b1v = (double)((const float*)&bc[1])[q];
            const double b2v = (double)((const float*)&bc[2])[q];
            const double b3v = (double)((const float*)&bc[3])[q];
            acc[0][0] = __builtin_amdgcn_mfma_f64_16x16x4f64(a0, b0,  acc[0][0], 0, 0, 0);
            acc[1][0] = __builtin_amdgcn_mfma_f64_16x16x4f64(a1, b0,  acc[1][0], 0, 0, 0);
            acc[0][1] = __builtin_amdgcn_mfma_f64_16x16x4f64(a0, b1v, acc[0][1], 0, 0, 0);
            acc[1][1] = __builtin_amdgcn_mfma_f64_16x16x4f64(a1, b1v, acc[1][1], 0, 0, 0);
            acc[0][2] = __builtin_amdgcn_mfma_f64_16x16x4f64(a0, b2v, acc[0][2], 0, 0, 0);
            acc[1][2] = __builtin_amdgcn_mfma_f64_16x16x4f64(a1, b2v, acc[1][2], 0, 0, 0);
            acc[0][3] = __builtin_amdgcn_mfma_f64_16x16x4f64(a0, b3v, acc[0][3], 0, 0, 0);
            acc[1][3] = __builtin_amdgcn_mfma_f64_16x16x4f64(a1, b3v, acc[1][3], 0, 0, 0);
        }
        #pragma unroll
        for (int q = 0; q < 8; ++q) ac[q] = an[q];
        #pragma unroll
        for (int q = 0; q < 4; ++q) bc[q] = bn[q];
    }
    #undef LOADB
    #undef LOADA

    if (var == 1 || var == 3) {
        // col = a15 (fixed per lane); row = 4g+v (var 1) or g+4v (var 3).
        double psum[2][4];
        #pragma unroll
        for (int mt = 0; mt < 2; ++mt)
            #pragma unroll
            for (int v = 0; v < 4; ++v) psum[mt][v] = 0.0;
        #pragma unroll
        for (int ot = 0; ot < 4; ++ot) {
            const int o = oc + ot * 16 + a15;
            const double bb = (double)b1[o];
            const double ww = (double)w2[o];
            #pragma unroll
            for (int mt = 0; mt < 2; ++mt)
                #pragma unroll
                for (int v = 0; v < 4; ++v) {
                    const double u = acc[mt][ot][v] + bb;
                    psum[mt][v] += ww * (u / (1.0 + exp(-u)));
                }
        }
        #pragma unroll
        for (int mt = 0; mt < 2; ++mt)
            #pragma unroll
            for (int v = 0; v < 4; ++v) {
                double x = psum[mt][v];
                x += __shfl_xor(x, 1, 64);
                x += __shfl_xor(x, 2, 64);
                x += __shfl_xor(x, 4, 64);
                x += __shfl_xor(x, 8, 64);
                psum[mt][v] = x;
            }
        if (a15 == 0) {
            #pragma unroll
            for (int mt = 0; mt < 2; ++mt)
                #pragma unroll
                for (int v = 0; v < 4; ++v) {
                    const int row = (var == 1) ? (4 * g + v) : (g + 4 * v);
                    spart[wave][mt * 16 + row] = psum[mt][v];
                }
        }
    } else {
        // row = a15 (fixed per lane); col = 4g+v (var 2) or g+4v (var 4).
        double ps[2] = {0.0, 0.0};
        #pragma unroll
        for (int ot = 0; ot < 4; ++ot)
            #pragma unroll
            for (int v = 0; v < 4; ++v) {
                const int cv = (var == 2) ? (4 * g + v) : (g + 4 * v);
                const int o = oc + ot * 16 + cv;
                const double bb = (double)b1[o];
                const double ww = (double)w2[o];
                #pragma unroll
                for (int mt = 0; mt < 2; ++mt) {
                    const double u = acc[mt][ot][v] + bb;
                    ps[mt] += ww * (u / (1.0 + exp(-u)));
                }
            }
        #pragma unroll
        for (int mt = 0; mt < 2; ++mt) {
            ps[mt] += __shfl_xor(ps[mt], 16, 64);
            ps[mt] += __shfl_xor(ps[mt], 32, 64);
        }
        if (g == 0) {
            spart[wave][a15]      = ps[0];
            spart[wave][16 + a15] = ps[1];
        }
    }
    __syncthreads();
    if (t < 32)
        s_out[m0 + t] = spart[0][t] + spart[1][t] + spart[2][t] + spart[3][t];
}

// VALU fallback (round-11 verified body, W1T layout): only if probe var==0.
__global__ __launch_bounds__(256)
__attribute__((amdgpu_waves_per_eu(2, 4)))
void s_valu_kernel(const float* __restrict__ hp, const float* __restrict__ W1T,
                   const float* __restrict__ b1, const float* __restrict__ w2,
                   double* __restrict__ s_out) {
    if (self_probe_var() != 0) return;
    const int t = threadIdx.x;
    const int lane = t & 63;
    const int wave = __builtin_amdgcn_readfirstlane(t >> 6);
    const int m0 = blockIdx.x * 16 + wave * 4;
    const int o0 = lane * 4;
    const float* hr = hp + (size_t)m0 * H_;
    const float* wp = W1T + o0;

    double acc[4][4];
    #pragma unroll
    for (int j = 0; j < 4; ++j)
        #pragma unroll
        for (int r = 0; r < 4; ++r) acc[j][r] = 0.0;

    float4 wA[8], wB[8];
    float hA[32], hB[32];

    #define LOADW(dst, kcv)                                                   \
        do {                                                                  \
            _Pragma("unroll")                                                 \
            for (int kk = 0; kk < 8; ++kk)                                    \
                dst[kk] = *reinterpret_cast<const float4*>(                   \
                    wp + (size_t)((kcv) + kk) * H_);                          \
        } while (0)

    #define LOADH(dst, kcv)                                                   \
        do {                                                                  \
            _Pragma("unroll")                                                 \
            for (int r = 0; r < 4; ++r)                                       \
                _Pragma("unroll")                                             \
                for (int kk = 0; kk < 8; ++kk)                                \
                    dst[r * 8 + kk] = hr[r * H_ + (kcv) + kk];                \
        } while (0)

    #define COMPUTE(wv, hbuf)                                                 \
        do {                                                                  \
            _Pragma("unroll")                                                 \
            for (int kk = 0; kk < 8; ++kk) {                                  \
                const double h0 = (double)hbuf[0 * 8 + kk];                   \
                const double h1 = (double)hbuf[1 * 8 + kk];                   \
                const double h2 = (double)hbuf[2 * 8 + kk];                   \
                const double h3 = (double)hbuf[3 * 8 + kk];                   \
                const double a0 = (double)wv[kk].x;                           \
                const double a1 = (double)wv[kk].y;                           \
                const double a2 = (double)wv[kk].z;                           \
                const double a3 = (double)wv[kk].w;                           \
                acc[0][0] = fma(a0, h0, acc[0][0]);                           \
                acc[0][1] = fma(a0, h1, acc[0][1]);                           \
                acc[0][2] = fma(a0, h2, acc[0][2]);                           \
                acc[0][3] = fma(a0, h3, acc[0][3]);                           \
                acc[1][0] = fma(a1, h0, acc[1][0]);                           \
                acc[1][1] = fma(a1, h1, acc[1][1]);                           \
                acc[1][2] = fma(a1, h2, acc[1][2]);                           \
                acc[1][3] = fma(a1, h3, acc[1][3]);                           \
                acc[2][0] = fma(a2, h0, acc[2][0]);                           \
                acc[2][1] = fma(a2, h1, acc[2][1]);                           \
                acc[2][2] = fma(a2, h2, acc[2][2]);                           \
                acc[2][3] = fma(a2, h3, acc[2][3]);                           \
                acc[3][0] = fma(a3, h0, acc[3][0]);                           \
                acc[3][1] = fma(a3, h1, acc[3][1]);                           \
                acc[3][2] = fma(a3, h2, acc[3][2]);                           \
                acc[3][3] = fma(a3, h3, acc[3][3]);                           \
            }                                                                 \
        } while (0)

    LOADW(wA, 0);
    LOADH(hA, 0);
    for (int kc = 0; kc < H_; kc += 16) {
        LOADW(wB, kc + 8);
        LOADH(hB, kc + 8);
        COMPUTE(wA, hA);
        if (kc + 16 < H_) {
            LOADW(wA, kc + 16);
            LOADH(hA, kc + 16);
        }
        COMPUTE(wB, hB);
    }
    #undef LOADW
    #undef LOADH
    #undef COMPUTE

    const float4 b1v = *reinterpret_cast<const float4*>(b1 + o0);
    const float4 w2v = *reinterpret_cast<const float4*>(w2 + o0);
    double psum[4] = {0.0, 0.0, 0.0, 0.0};
    #define EPI(j, bc, wc)                                                    \
        do {                                                                  \
            const double bb = (double)bc, ww = (double)wc;                    \
            _Pragma("unroll")                                                 \
            for (int r = 0; r < 4; ++r) {                                     \
                const double u = acc[j][r] + bb;                              \
                psum[r] += ww * (u / (1.0 + exp(-u)));                        \
            }                                                                 \
        } while (0)
    EPI(0, b1v.x, w2v.x);
    EPI(1, b1v.y, w2v.y);
    EPI(2, b1v.z, w2v.z);
    EPI(3, b1v.w, w2v.w);
    #undef EPI

    #pragma unroll
    for (int r = 0; r < 4; ++r) {
        double v = psum[r];
        v += __shfl_xor(v, 1, 64);
        v += __shfl_xor(v, 2, 64);
        v += __shfl_xor(v, 4, 64);
        v += __shfl_xor(v, 8, 64);
        v += __shfl_xor(v, 16, 64);
        v += __shfl_xor(v, 32, 64);
        if (lane == 0) s_out[m0 + r] = v;
    }
}

// Kernel B: out[b,i,j] = (int32)trunc( (s[b,i] - s[b,j]) + b2 )
__global__ __launch_bounds__(256)
void pair_kernel(const double* __restrict__ s, const float* __restrict__ b2p,
                 int* __restrict__ out) {
    const double b2 = (double)b2p[0];
    const unsigned total4 = (unsigned)(B_) * (unsigned)(N_) * (unsigned)(N_) / 4u;
    const unsigned stride = gridDim.x * blockDim.x;
    for (unsigned idx = blockIdx.x * blockDim.x + threadIdx.x; idx < total4;
         idx += stride) {
        const unsigned base = idx * 4u;                 // element index, %4==0
        const unsigned bi  = base >> 22;                // / (N*N), N*N = 2^22
        const unsigned rem = base & ((1u << 22) - 1u);
        const unsigned i   = rem >> 11;                 // / N
        const unsigned j   = rem & (N_ - 1u);
        const double si = s[bi * N_ + i];
        const double* sp = s + bi * N_ + j;             // 32B aligned (j%4==0)
        const double sj0 = sp[0], sj1 = sp[1], sj2 = sp[2], sj3 = sp[3];
        int4 o;
        o.x = (int)trunc((si - sj0) + b2);
        o.y = (int)trunc((si - sj1) + b2);
        o.z = (int)trunc((si - sj2) + b2);
        o.w = (int)trunc((si - sj3) + b2);
        *reinterpret_cast<int4*>(out + base) = o;
    }
}

extern "C" void kernel_launch(void* const* d_in, const int* in_sizes, int n_in,
                              void* d_out, int out_size, void* d_ws, size_t ws_size,
                              hipStream_t stream) {
    const float* hp = (const float*)d_in[0];
    // d_in[1] = node_mask (unused), d_in[2] = n_nodes (unused)
    const float* W1 = (const float*)d_in[3];
    const float* b1 = (const float*)d_in[4];
    const float* w2 = (const float*)d_in[5];
    const float* b2 = (const float*)d_in[6];

    float*  W1T = (float*)d_ws;                                   // 256 KB
    float*  W1P = (float*)((char*)d_ws + 256 * 1024);             // 256 KB
    double* s   = (double*)((char*)d_ws + 512 * 1024);            // 128 KB
    int* out = (int*)d_out;

    transpose_w1<<<H_, H_, 0, stream>>>(W1, W1T);
    pack_w1<<<H_, H_, 0, stream>>>(W1, W1P);
    s_mfma_uni<<<(B_ * N_) / 32, 256, 0, stream>>>(hp, W1P, b1, w2, s);
    s_valu_kernel<<<(B_ * N_) / 16, 256, 0, stream>>>(hp, W1T, b1, w2, s);
    pair_kernel<<<2048, 256, 0, stream>>>(s, b2, out);
}

// Round 20
// 80.137 us; speedup vs baseline: 1.3724x; 1.1167x over previous
//
#include <hip/hip_runtime.h>
#include <math.h>

#define B_ 8
#define N_ 2048
#define H_ 256

typedef double d4 __attribute__((ext_vector_type(4)));

// One-shot: W1T[k][o] = W1[o][k] (f32). Used by BOTH s-kernels: consecutive
// lanes read consecutive o -> coalesced (round-19 lesson: lane coalescing
// beats per-lane load width; packed-B float4 layout was 1KB-strided across
// lanes and regressed 52 -> 65 us).
__global__ __launch_bounds__(256)
void transpose_w1(const float* __restrict__ W1, float* __restrict__ W1T) {
    W1T[(size_t)blockIdx.x * H_ + threadIdx.x] =
        W1[(size_t)threadIdx.x * H_ + blockIdx.x];
}

// In-kernel probe of the v_mfma_f64_16x16x4_f64 lane mapping (~200 cy).
// Rounds 15-18 proved one of vars 1-4 matches on this chip.
__device__ __forceinline__ int self_probe_var() {
    const int l = threadIdx.x & 63;
    d4 z = {0.0, 0.0, 0.0, 0.0};
    d4 r1 = __builtin_amdgcn_mfma_f64_16x16x4f64((double)(l + 1), 1.0, z, 0, 0, 0);
    d4 r2 = __builtin_amdgcn_mfma_f64_16x16x4f64(1.0, (double)(l + 1), z, 0, 0, 0);
    d4 r3 = __builtin_amdgcn_mfma_f64_16x16x4f64((double)(l & 15), 1.0, z, 0, 0, 0);
    const double pw0 = __shfl(r1[0], 0, 64);
    const double pw1 = __shfl(r2[0], 0, 64);
    const double pw2 = __shfl(r3[0], 1, 64);
    const double pw3 = __shfl(r3[2], 16, 64);
    const double pw4 = __shfl(r2[2], 16, 64);
    if (pw0 != 100.0 || pw1 != 100.0) return 0;
    if (pw2 == 0.0 && pw3 == 24.0)  return 1;   // row=4g+v, col=a15
    if (pw2 == 0.0 && pw3 == 36.0)  return 3;   // row=g+4v, col=a15
    if (pw2 == 4.0 && pw4 == 124.0) return 2;   // row=a15,  col=4g+v
    if (pw2 == 4.0 && pw4 == 136.0) return 4;   // row=a15,  col=g+4v
    return 0;
}

// MFMA s-kernel, round-20: r17's verified per-wave body + split-K in-block.
// Block = 512 thr = 8 waves = (kh in {0,1}) x (ow in 0..3); 32 rows/block,
// grid 512 -> 16 waves/CU = 4 waves/SIMD (r17 had 2). Wave = 2 m-tiles x
// 4 o-tiles over K/2: per 8-k iter 16 mfma (1024 cy pipe) vs 12 coalesced
// scalar loads. kh-partials combined in LDS in register-coordinate space
// (mapping-independent); kh=1 waves run the var-dependent epilogue.
__global__ __launch_bounds__(512)
__attribute__((amdgpu_waves_per_eu(2, 4)))
void s_mfma_uni(const float* __restrict__ hp, const float* __restrict__ W1T,
                const float* __restrict__ b1, const float* __restrict__ w2,
                double* __restrict__ s_out) {
    const int var = self_probe_var();
    if (var == 0) return;                       // VALU fallback does the work
    __shared__ double u_lds[4][32][64];         // [ow][idx][lane], 64 KB
    __shared__ double spart[4][32];
    const int t = threadIdx.x;
    const int lane = t & 63;
    const int w = __builtin_amdgcn_readfirstlane(t >> 6);
    const int kh = w >> 2;                      // K half
    const int ow = w & 3;                       // o strip
    const int a15 = lane & 15, g = lane >> 4;
    const int m0 = blockIdx.x * 32;
    const int oc = ow * 64;
    const int K0 = kh * 128;
    // A: h[m0 + mt*16 + a15][k + g]; B: W1T[k + g][oc + ot*16 + a15]
    const float* ap0 = hp + (size_t)(m0 + a15) * H_ + g + K0;
    const float* ap1 = ap0 + 16 * H_;
    const float* bp  = W1T + (size_t)(K0 + g) * H_ + oc + a15;

    d4 acc[2][4];
    #pragma unroll
    for (int mt = 0; mt < 2; ++mt)
        #pragma unroll
        for (int ot = 0; ot < 4; ++ot) acc[mt][ot] = (d4){0.0, 0.0, 0.0, 0.0};

    float ac[4], an[4];        // A: [mt*2 + half]
    float bcv[8], bnv[8];      // B: [half*4 + ot]
    ac[0] = ap0[0]; ac[1] = ap0[4]; ac[2] = ap1[0]; ac[3] = ap1[4];
    #pragma unroll
    for (int ot = 0; ot < 4; ++ot) {
        bcv[ot]     = bp[ot * 16];
        bcv[4 + ot] = bp[4 * H_ + ot * 16];
    }

    for (int kc = 0; kc < 128; kc += 8) {
        const int kn = (kc + 8 < 128) ? (kc + 8) : 0;     // guarded prefetch
        an[0] = ap0[kn]; an[1] = ap0[kn + 4];
        an[2] = ap1[kn]; an[3] = ap1[kn + 4];
        #pragma unroll
        for (int ot = 0; ot < 4; ++ot) {
            bnv[ot]     = bp[(size_t)kn * H_ + ot * 16];
            bnv[4 + ot] = bp[(size_t)(kn + 4) * H_ + ot * 16];
        }
        {   // k half 0 (k = kc..kc+3)
            const double a0 = (double)ac[0], a1 = (double)ac[2];
            #pragma unroll
            for (int ot = 0; ot < 4; ++ot) {
                const double bv = (double)bcv[ot];
                acc[0][ot] = __builtin_amdgcn_mfma_f64_16x16x4f64(a0, bv, acc[0][ot], 0, 0, 0);
                acc[1][ot] = __builtin_amdgcn_mfma_f64_16x16x4f64(a1, bv, acc[1][ot], 0, 0, 0);
            }
        }
        {   // k half 1 (k = kc+4..kc+7)
            const double a0 = (double)ac[1], a1 = (double)ac[3];
            #pragma unroll
            for (int ot = 0; ot < 4; ++ot) {
                const double bv = (double)bcv[4 + ot];
                acc[0][ot] = __builtin_amdgcn_mfma_f64_16x16x4f64(a0, bv, acc[0][ot], 0, 0, 0);
                acc[1][ot] = __builtin_amdgcn_mfma_f64_16x16x4f64(a1, bv, acc[1][ot], 0, 0, 0);
            }
        }
        #pragma unroll
        for (int q = 0; q < 4; ++q) ac[q] = an[q];
        #pragma unroll
        for (int q = 0; q < 8; ++q) bcv[q] = bnv[q];
    }

    // Cross-kh combine in register-coordinate space (mapping-independent).
    if (kh == 0) {
        #pragma unroll
        for (int mt = 0; mt < 2; ++mt)
            #pragma unroll
            for (int ot = 0; ot < 4; ++ot)
                #pragma unroll
                for (int v = 0; v < 4; ++v)
                    u_lds[ow][mt * 16 + ot * 4 + v][lane] = acc[mt][ot][v];
    }
    __syncthreads();
    if (kh == 1) {
        #pragma unroll
        for (int mt = 0; mt < 2; ++mt)
            #pragma unroll
            for (int ot = 0; ot < 4; ++ot)
                #pragma unroll
                for (int v = 0; v < 4; ++v)
                    acc[mt][ot][v] += u_lds[ow][mt * 16 + ot * 4 + v][lane];

        if (var == 1 || var == 3) {
            // col = a15 (per lane); row = 4g+v (var 1) or g+4v (var 3).
            double psum[2][4];
            #pragma unroll
            for (int mt = 0; mt < 2; ++mt)
                #pragma unroll
                for (int v = 0; v < 4; ++v) psum[mt][v] = 0.0;
            #pragma unroll
            for (int ot = 0; ot < 4; ++ot) {
                const int o = oc + ot * 16 + a15;
                const double bb = (double)b1[o];
                const double ww = (double)w2[o];
                #pragma unroll
                for (int mt = 0; mt < 2; ++mt)
                    #pragma unroll
                    for (int v = 0; v < 4; ++v) {
                        const double u = acc[mt][ot][v] + bb;
                        psum[mt][v] += ww * (u / (1.0 + exp(-u)));
                    }
            }
            #pragma unroll
            for (int mt = 0; mt < 2; ++mt)
                #pragma unroll
                for (int v = 0; v < 4; ++v) {
                    double x = psum[mt][v];
                    x += __shfl_xor(x, 1, 64);
                    x += __shfl_xor(x, 2, 64);
                    x += __shfl_xor(x, 4, 64);
                    x += __shfl_xor(x, 8, 64);
                    psum[mt][v] = x;
                }
            if (a15 == 0) {
                #pragma unroll
                for (int mt = 0; mt < 2; ++mt)
                    #pragma unroll
                    for (int v = 0; v < 4; ++v) {
                        const int row = (var == 1) ? (4 * g + v) : (g + 4 * v);
                        spart[ow][mt * 16 + row] = psum[mt][v];
                    }
            }
        } else {
            // row = a15 (per lane); col = 4g+v (var 2) or g+4v (var 4).
            double ps[2] = {0.0, 0.0};
            #pragma unroll
            for (int ot = 0; ot < 4; ++ot)
                #pragma unroll
                for (int v = 0; v < 4; ++v) {
                    const int cv = (var == 2) ? (4 * g + v) : (g + 4 * v);
                    const int o = oc + ot * 16 + cv;
                    const double bb = (double)b1[o];
                    const double ww = (double)w2[o];
                    #pragma unroll
                    for (int mt = 0; mt < 2; ++mt) {
                        const double u = acc[mt][ot][v] + bb;
                        ps[mt] += ww * (u / (1.0 + exp(-u)));
                    }
                }
            #pragma unroll
            for (int mt = 0; mt < 2; ++mt) {
                ps[mt] += __shfl_xor(ps[mt], 16, 64);
                ps[mt] += __shfl_xor(ps[mt], 32, 64);
            }
            if (g == 0) {
                spart[ow][a15]      = ps[0];
                spart[ow][16 + a15] = ps[1];
            }
        }
    }
    __syncthreads();
    if (t < 32)
        s_out[m0 + t] = spart[0][t] + spart[1][t] + spart[2][t] + spart[3][t];
}

// VALU fallback (round-11 verified body, W1T layout): only if probe var==0.
__global__ __launch_bounds__(256)
__attribute__((amdgpu_waves_per_eu(2, 4)))
void s_valu_kernel(const float* __restrict__ hp, const float* __restrict__ W1T,
                   const float* __restrict__ b1, const float* __restrict__ w2,
                   double* __restrict__ s_out) {
    if (self_probe_var() != 0) return;
    const int t = threadIdx.x;
    const int lane = t & 63;
    const int wave = __builtin_amdgcn_readfirstlane(t >> 6);
    const int m0 = blockIdx.x * 16 + wave * 4;
    const int o0 = lane * 4;
    const float* hr = hp + (size_t)m0 * H_;
    const float* wp = W1T + o0;

    double acc[4][4];
    #pragma unroll
    for (int j = 0; j < 4; ++j)
        #pragma unroll
        for (int r = 0; r < 4; ++r) acc[j][r] = 0.0;

    float4 wA[8], wB[8];
    float hA[32], hB[32];

    #define LOADW(dst, kcv)                                                   \
        do {                                                                  \
            _Pragma("unroll")                                                 \
            for (int kk = 0; kk < 8; ++kk)                                    \
                dst[kk] = *reinterpret_cast<const float4*>(                   \
                    wp + (size_t)((kcv) + kk) * H_);                          \
        } while (0)

    #define LOADH(dst, kcv)                                                   \
        do {                                                                  \
            _Pragma("unroll")                                                 \
            for (int r = 0; r < 4; ++r)                                       \
                _Pragma("unroll")                                             \
                for (int kk = 0; kk < 8; ++kk)                                \
                    dst[r * 8 + kk] = hr[r * H_ + (kcv) + kk];                \
        } while (0)

    #define COMPUTE(wv, hbuf)                                                 \
        do {                                                                  \
            _Pragma("unroll")                                                 \
            for (int kk = 0; kk < 8; ++kk) {                                  \
                const double h0 = (double)hbuf[0 * 8 + kk];                   \
                const double h1 = (double)hbuf[1 * 8 + kk];                   \
                const double h2 = (double)hbuf[2 * 8 + kk];                   \
                const double h3 = (double)hbuf[3 * 8 + kk];                   \
                const double a0 = (double)wv[kk].x;                           \
                const double a1 = (double)wv[kk].y;                           \
                const double a2 = (double)wv[kk].z;                           \
                const double a3 = (double)wv[kk].w;                           \
                acc[0][0] = fma(a0, h0, acc[0][0]);                           \
                acc[0][1] = fma(a0, h1, acc[0][1]);                           \
                acc[0][2] = fma(a0, h2, acc[0][2]);                           \
                acc[0][3] = fma(a0, h3, acc[0][3]);                           \
                acc[1][0] = fma(a1, h0, acc[1][0]);                           \
                acc[1][1] = fma(a1, h1, acc[1][1]);                           \
                acc[1][2] = fma(a1, h2, acc[1][2]);                           \
                acc[1][3] = fma(a1, h3, acc[1][3]);                           \
                acc[2][0] = fma(a2, h0, acc[2][0]);                           \
                acc[2][1] = fma(a2, h1, acc[2][1]);                           \
                acc[2][2] = fma(a2, h2, acc[2][2]);                           \
                acc[2][3] = fma(a2, h3, acc[2][3]);                           \
                acc[3][0] = fma(a3, h0, acc[3][0]);                           \
                acc[3][1] = fma(a3, h1, acc[3][1]);                           \
                acc[3][2] = fma(a3, h2, acc[3][2]);                           \
                acc[3][3] = fma(a3, h3, acc[3][3]);                           \
            }                                                                 \
        } while (0)

    LOADW(wA, 0);
    LOADH(hA, 0);
    for (int kc = 0; kc < H_; kc += 16) {
        LOADW(wB, kc + 8);
        LOADH(hB, kc + 8);
        COMPUTE(wA, hA);
        if (kc + 16 < H_) {
            LOADW(wA, kc + 16);
            LOADH(hA, kc + 16);
        }
        COMPUTE(wB, hB);
    }
    #undef LOADW
    #undef LOADH
    #undef COMPUTE

    const float4 b1v = *reinterpret_cast<const float4*>(b1 + o0);
    const float4 w2v = *reinterpret_cast<const float4*>(w2 + o0);
    double psum[4] = {0.0, 0.0, 0.0, 0.0};
    #define EPI(j, bc, wc)                                                    \
        do {                                                                  \
            const double bb = (double)bc, ww = (double)wc;                    \
            _Pragma("unroll")                                                 \
            for (int r = 0; r < 4; ++r) {                                     \
                const double u = acc[j][r] + bb;                              \
                psum[r] += ww * (u / (1.0 + exp(-u)));                        \
            }                                                                 \
        } while (0)
    EPI(0, b1v.x, w2v.x);
    EPI(1, b1v.y, w2v.y);
    EPI(2, b1v.z, w2v.z);
    EPI(3, b1v.w, w2v.w);
    #undef EPI

    #pragma unroll
    for (int r = 0; r < 4; ++r) {
        double v = psum[r];
        v += __shfl_xor(v, 1, 64);
        v += __shfl_xor(v, 2, 64);
        v += __shfl_xor(v, 4, 64);
        v += __shfl_xor(v, 8, 64);
        v += __shfl_xor(v, 16, 64);
        v += __shfl_xor(v, 32, 64);
        if (lane == 0) s_out[m0 + r] = v;
    }
}

// Kernel B: out[b,i,j] = (int32)trunc( (s[b,i] - s[b,j]) + b2 )
__global__ __launch_bounds__(256)
void pair_kernel(const double* __restrict__ s, const float* __restrict__ b2p,
                 int* __restrict__ out) {
    const double b2 = (double)b2p[0];
    const unsigned total4 = (unsigned)(B_) * (unsigned)(N_) * (unsigned)(N_) / 4u;
    const unsigned stride = gridDim.x * blockDim.x;
    for (unsigned idx = blockIdx.x * blockDim.x + threadIdx.x; idx < total4;
         idx += stride) {
        const unsigned base = idx * 4u;                 // element index, %4==0
        const unsigned bi  = base >> 22;                // / (N*N), N*N = 2^22
        const unsigned rem = base & ((1u << 22) - 1u);
        const unsigned i   = rem >> 11;                 // / N
        const unsigned j   = rem & (N_ - 1u);
        const double si = s[bi * N_ + i];
        const double* sp = s + bi * N_ + j;             // 32B aligned (j%4==0)
        const double sj0 = sp[0], sj1 = sp[1], sj2 = sp[2], sj3 = sp[3];
        int4 o;
        o.x = (int)trunc((si - sj0) + b2);
        o.y = (int)trunc((si - sj1) + b2);
        o.z = (int)trunc((si - sj2) + b2);
        o.w = (int)trunc((si - sj3) + b2);
        *reinterpret_cast<int4*>(out + base) = o;
    }
}

extern "C" void kernel_launch(void* const* d_in, const int* in_sizes, int n_in,
                              void* d_out, int out_size, void* d_ws, size_t ws_size,
                              hipStream_t stream) {
    const float* hp = (const float*)d_in[0];
    // d_in[1] = node_mask (unused), d_in[2] = n_nodes (unused)
    const float* W1 = (const float*)d_in[3];
    const float* b1 = (const float*)d_in[4];
    const float* w2 = (const float*)d_in[5];
    const float* b2 = (const float*)d_in[6];

    float*  W1T = (float*)d_ws;                                   // 256 KB
    double* s   = (double*)((char*)d_ws + 256 * 1024);            // 128 KB
    int* out = (int*)d_out;

    transpose_w1<<<H_, H_, 0, stream>>>(W1, W1T);
    s_mfma_uni<<<(B_ * N_) / 32, 512, 0, stream>>>(hp, W1T, b1, w2, s);
    s_valu_kernel<<<(B_ * N_) / 16, 256, 0, stream>>>(hp, W1T, b1, w2, s);
    pair_kernel<<<2048, 256, 0, stream>>>(s, b2, out);
}

// Round 21
// 76.091 us; speedup vs baseline: 1.4454x; 1.0532x over previous
//
#include <hip/hip_runtime.h>
#include <math.h>

#define B_ 8
#define N_ 2048
#define H_ 256

typedef double d4 __attribute__((ext_vector_type(4)));

// One-shot: W1T[k][o] = W1[o][k] (f32). Consecutive lanes read consecutive
// o -> coalesced (r19 lesson: lane coalescing beats per-lane load width).
__global__ __launch_bounds__(256)
void transpose_w1(const float* __restrict__ W1, float* __restrict__ W1T) {
    W1T[(size_t)blockIdx.x * H_ + threadIdx.x] =
        W1[(size_t)threadIdx.x * H_ + blockIdx.x];
}

// In-kernel probe of the v_mfma_f64_16x16x4_f64 lane mapping (~200 cy).
// Rounds 15-18 proved one of vars 1-4 matches on this chip.
__device__ __forceinline__ int self_probe_var() {
    const int l = threadIdx.x & 63;
    d4 z = {0.0, 0.0, 0.0, 0.0};
    d4 r1 = __builtin_amdgcn_mfma_f64_16x16x4f64((double)(l + 1), 1.0, z, 0, 0, 0);
    d4 r2 = __builtin_amdgcn_mfma_f64_16x16x4f64(1.0, (double)(l + 1), z, 0, 0, 0);
    d4 r3 = __builtin_amdgcn_mfma_f64_16x16x4f64((double)(l & 15), 1.0, z, 0, 0, 0);
    const double pw0 = __shfl(r1[0], 0, 64);
    const double pw1 = __shfl(r2[0], 0, 64);
    const double pw2 = __shfl(r3[0], 1, 64);
    const double pw3 = __shfl(r3[2], 16, 64);
    const double pw4 = __shfl(r2[2], 16, 64);
    if (pw0 != 100.0 || pw1 != 100.0) return 0;
    if (pw2 == 0.0 && pw3 == 24.0)  return 1;   // row=4g+v, col=a15
    if (pw2 == 0.0 && pw3 == 36.0)  return 3;   // row=g+4v, col=a15
    if (pw2 == 4.0 && pw4 == 124.0) return 2;   // row=a15,  col=4g+v
    if (pw2 == 4.0 && pw4 == 136.0) return 4;   // row=a15,  col=g+4v
    return 0;
}

// MFMA s-kernel, round-21: r17's proven geometry (32 rows/block, grid 512,
// 4 waves, wave = 2 m-tiles x 4 o-tiles, 16 mfma per 8-k iter) + the h-tile
// staged in LDS once (coalesced f32, 32 KB). A-fragment reads become LDS
// broadcasts (free, ~120 cy) instead of first-touch HBM loads (~900 cy,
// 16-line overfetch) that the 1024-cy mfma burst could not reliably hide —
// the suspected 47% idle in r17. B stays as coalesced scalar loads from
// L2-resident W1T, prefetched one iteration ahead.
__global__ __launch_bounds__(256)
__attribute__((amdgpu_waves_per_eu(2, 4)))
void s_mfma_uni(const float* __restrict__ hp, const float* __restrict__ W1T,
                const float* __restrict__ b1, const float* __restrict__ w2,
                double* __restrict__ s_out) {
    const int var = self_probe_var();
    if (var == 0) return;                       // VALU fallback does the work
    __shared__ float hs[32][H_];                // 32 KB
    __shared__ double spart[4][32];
    const int t = threadIdx.x;
    const int lane = t & 63;
    const int wave = __builtin_amdgcn_readfirstlane(t >> 6);
    const int a15 = lane & 15, g = lane >> 4;
    const int m0 = blockIdx.x * 32;
    const int oc = wave * 64;

    // Stage the 32-row h tile (coalesced: 1 KB per row per wave-load).
    #pragma unroll
    for (int i = 0; i < 32; ++i)
        hs[i][t] = hp[(size_t)(m0 + i) * H_ + t];
    __syncthreads();

    // B: W1T[k + g][oc + ot*16 + a15] — consecutive a15 lanes -> consecutive
    // floats (coalesced); g picks the k-row.
    const float* bp = W1T + (size_t)g * H_ + oc + a15;

    d4 acc[2][4];
    #pragma unroll
    for (int mt = 0; mt < 2; ++mt)
        #pragma unroll
        for (int ot = 0; ot < 4; ++ot) acc[mt][ot] = (d4){0.0, 0.0, 0.0, 0.0};

    float ac[4], an[4];        // A: [mt*2 + half], from LDS broadcast
    float bcv[8], bnv[8];      // B: [half*4 + ot]
    ac[0] = hs[a15][g];      ac[1] = hs[a15][4 + g];
    ac[2] = hs[16 + a15][g]; ac[3] = hs[16 + a15][4 + g];
    #pragma unroll
    for (int ot = 0; ot < 4; ++ot) {
        bcv[ot]     = bp[ot * 16];
        bcv[4 + ot] = bp[4 * H_ + ot * 16];
    }

    for (int kc = 0; kc < H_; kc += 8) {
        const int kn = (kc + 8 < H_) ? (kc + 8) : 0;      // guarded prefetch
        an[0] = hs[a15][kn + g];      an[1] = hs[a15][kn + 4 + g];
        an[2] = hs[16 + a15][kn + g]; an[3] = hs[16 + a15][kn + 4 + g];
        #pragma unroll
        for (int ot = 0; ot < 4; ++ot) {
            bnv[ot]     = bp[(size_t)kn * H_ + ot * 16];
            bnv[4 + ot] = bp[(size_t)(kn + 4) * H_ + ot * 16];
        }
        {   // k half 0 (k = kc..kc+3)
            const double a0 = (double)ac[0], a1 = (double)ac[2];
            #pragma unroll
            for (int ot = 0; ot < 4; ++ot) {
                const double bv = (double)bcv[ot];
                acc[0][ot] = __builtin_amdgcn_mfma_f64_16x16x4f64(a0, bv, acc[0][ot], 0, 0, 0);
                acc[1][ot] = __builtin_amdgcn_mfma_f64_16x16x4f64(a1, bv, acc[1][ot], 0, 0, 0);
            }
        }
        {   // k half 1 (k = kc+4..kc+7)
            const double a0 = (double)ac[1], a1 = (double)ac[3];
            #pragma unroll
            for (int ot = 0; ot < 4; ++ot) {
                const double bv = (double)bcv[4 + ot];
                acc[0][ot] = __builtin_amdgcn_mfma_f64_16x16x4f64(a0, bv, acc[0][ot], 0, 0, 0);
                acc[1][ot] = __builtin_amdgcn_mfma_f64_16x16x4f64(a1, bv, acc[1][ot], 0, 0, 0);
            }
        }
        #pragma unroll
        for (int q = 0; q < 4; ++q) ac[q] = an[q];
        #pragma unroll
        for (int q = 0; q < 8; ++q) bcv[q] = bnv[q];
    }

    if (var == 1 || var == 3) {
        // col = a15 (per lane); row = 4g+v (var 1) or g+4v (var 3).
        double psum[2][4];
        #pragma unroll
        for (int mt = 0; mt < 2; ++mt)
            #pragma unroll
            for (int v = 0; v < 4; ++v) psum[mt][v] = 0.0;
        #pragma unroll
        for (int ot = 0; ot < 4; ++ot) {
            const int o = oc + ot * 16 + a15;
            const double bb = (double)b1[o];
            const double ww = (double)w2[o];
            #pragma unroll
            for (int mt = 0; mt < 2; ++mt)
                #pragma unroll
                for (int v = 0; v < 4; ++v) {
                    const double u = acc[mt][ot][v] + bb;
                    psum[mt][v] += ww * (u / (1.0 + exp(-u)));
                }
        }
        #pragma unroll
        for (int mt = 0; mt < 2; ++mt)
            #pragma unroll
            for (int v = 0; v < 4; ++v) {
                double x = psum[mt][v];
                x += __shfl_xor(x, 1, 64);
                x += __shfl_xor(x, 2, 64);
                x += __shfl_xor(x, 4, 64);
                x += __shfl_xor(x, 8, 64);
                psum[mt][v] = x;
            }
        if (a15 == 0) {
            #pragma unroll
            for (int mt = 0; mt < 2; ++mt)
                #pragma unroll
                for (int v = 0; v < 4; ++v) {
                    const int row = (var == 1) ? (4 * g + v) : (g + 4 * v);
                    spart[wave][mt * 16 + row] = psum[mt][v];
                }
        }
    } else {
        // row = a15 (per lane); col = 4g+v (var 2) or g+4v (var 4).
        double ps[2] = {0.0, 0.0};
        #pragma unroll
        for (int ot = 0; ot < 4; ++ot)
            #pragma unroll
            for (int v = 0; v < 4; ++v) {
                const int cv = (var == 2) ? (4 * g + v) : (g + 4 * v);
                const int o = oc + ot * 16 + cv;
                const double bb = (double)b1[o];
                const double ww = (double)w2[o];
                #pragma unroll
                for (int mt = 0; mt < 2; ++mt) {
                    const double u = acc[mt][ot][v] + bb;
                    ps[mt] += ww * (u / (1.0 + exp(-u)));
                }
            }
        #pragma unroll
        for (int mt = 0; mt < 2; ++mt) {
            ps[mt] += __shfl_xor(ps[mt], 16, 64);
            ps[mt] += __shfl_xor(ps[mt], 32, 64);
        }
        if (g == 0) {
            spart[wave][a15]      = ps[0];
            spart[wave][16 + a15] = ps[1];
        }
    }
    __syncthreads();
    if (t < 32)
        s_out[m0 + t] = spart[0][t] + spart[1][t] + spart[2][t] + spart[3][t];
}

// VALU fallback (round-11 verified body, W1T layout): only if probe var==0.
__global__ __launch_bounds__(256)
__attribute__((amdgpu_waves_per_eu(2, 4)))
void s_valu_kernel(const float* __restrict__ hp, const float* __restrict__ W1T,
                   const float* __restrict__ b1, const float* __restrict__ w2,
                   double* __restrict__ s_out) {
    if (self_probe_var() != 0) return;
    const int t = threadIdx.x;
    const int lane = t & 63;
    const int wave = __builtin_amdgcn_readfirstlane(t >> 6);
    const int m0 = blockIdx.x * 16 + wave * 4;
    const int o0 = lane * 4;
    const float* hr = hp + (size_t)m0 * H_;
    const float* wp = W1T + o0;

    double acc[4][4];
    #pragma unroll
    for (int j = 0; j < 4; ++j)
        #pragma unroll
        for (int r = 0; r < 4; ++r) acc[j][r] = 0.0;

    float4 wA[8], wB[8];
    float hA[32], hB[32];

    #define LOADW(dst, kcv)                                                   \
        do {                                                                  \
            _Pragma("unroll")                                                 \
            for (int kk = 0; kk < 8; ++kk)                                    \
                dst[kk] = *reinterpret_cast<const float4*>(                   \
                    wp + (size_t)((kcv) + kk) * H_);                          \
        } while (0)

    #define LOADH(dst, kcv)                                                   \
        do {                                                                  \
            _Pragma("unroll")                                                 \
            for (int r = 0; r < 4; ++r)                                       \
                _Pragma("unroll")                                             \
                for (int kk = 0; kk < 8; ++kk)                                \
                    dst[r * 8 + kk] = hr[r * H_ + (kcv) + kk];                \
        } while (0)

    #define COMPUTE(wv, hbuf)                                                 \
        do {                                                                  \
            _Pragma("unroll")                                                 \
            for (int kk = 0; kk < 8; ++kk) {                                  \
                const double h0 = (double)hbuf[0 * 8 + kk];                   \
                const double h1 = (double)hbuf[1 * 8 + kk];                   \
                const double h2 = (double)hbuf[2 * 8 + kk];                   \
                const double h3 = (double)hbuf[3 * 8 + kk];                   \
                const double a0 = (double)wv[kk].x;                           \
                const double a1 = (double)wv[kk].y;                           \
                const double a2 = (double)wv[kk].z;                           \
                const double a3 = (double)wv[kk].w;                           \
                acc[0][0] = fma(a0, h0, acc[0][0]);                           \
                acc[0][1] = fma(a0, h1, acc[0][1]);                           \
                acc[0][2] = fma(a0, h2, acc[0][2]);                           \
                acc[0][3] = fma(a0, h3, acc[0][3]);                           \
                acc[1][0] = fma(a1, h0, acc[1][0]);                           \
                acc[1][1] = fma(a1, h1, acc[1][1]);                           \
                acc[1][2] = fma(a1, h2, acc[1][2]);                           \
                acc[1][3] = fma(a1, h3, acc[1][3]);                           \
                acc[2][0] = fma(a2, h0, acc[2][0]);                           \
                acc[2][1] = fma(a2, h1, acc[2][1]);                           \
                acc[2][2] = fma(a2, h2, acc[2][2]);                           \
                acc[2][3] = fma(a2, h3, acc[2][3]);                           \
                acc[3][0] = fma(a3, h0, acc[3][0]);                           \
                acc[3][1] = fma(a3, h1, acc[3][1]);                           \
                acc[3][2] = fma(a3, h2, acc[3][2]);                           \
                acc[3][3] = fma(a3, h3, acc[3][3]);                           \
            }                                                                 \
        } while (0)

    LOADW(wA, 0);
    LOADH(hA, 0);
    for (int kc = 0; kc < H_; kc += 16) {
        LOADW(wB, kc + 8);
        LOADH(hB, kc + 8);
        COMPUTE(wA, hA);
        if (kc + 16 < H_) {
            LOADW(wA, kc + 16);
            LOADH(hA, kc + 16);
        }
        COMPUTE(wB, hB);
    }
    #undef LOADW
    #undef LOADH
    #undef COMPUTE

    const float4 b1v = *reinterpret_cast<const float4*>(b1 + o0);
    const float4 w2v = *reinterpret_cast<const float4*>(w2 + o0);
    double psum[4] = {0.0, 0.0, 0.0, 0.0};
    #define EPI(j, bc, wc)                                                    \
        do {                                                                  \
            const double bb = (double)bc, ww = (double)wc;                    \
            _Pragma("unroll")                                                 \
            for (int r = 0; r < 4; ++r) {                                     \
                const double u = acc[j][r] + bb;                              \
                psum[r] += ww * (u / (1.0 + exp(-u)));                        \
            }                                                                 \
        } while (0)
    EPI(0, b1v.x, w2v.x);
    EPI(1, b1v.y, w2v.y);
    EPI(2, b1v.z, w2v.z);
    EPI(3, b1v.w, w2v.w);
    #undef EPI

    #pragma unroll
    for (int r = 0; r < 4; ++r) {
        double v = psum[r];
        v += __shfl_xor(v, 1, 64);
        v += __shfl_xor(v, 2, 64);
        v += __shfl_xor(v, 4, 64);
        v += __shfl_xor(v, 8, 64);
        v += __shfl_xor(v, 16, 64);
        v += __shfl_xor(v, 32, 64);
        if (lane == 0) s_out[m0 + r] = v;
    }
}

// Kernel B: out[b,i,j] = (int32)trunc( (s[b,i] - s[b,j]) + b2 )
__global__ __launch_bounds__(256)
void pair_kernel(const double* __restrict__ s, const float* __restrict__ b2p,
                 int* __restrict__ out) {
    const double b2 = (double)b2p[0];
    const unsigned total4 = (unsigned)(B_) * (unsigned)(N_) * (unsigned)(N_) / 4u;
    const unsigned stride = gridDim.x * blockDim.x;
    for (unsigned idx = blockIdx.x * blockDim.x + threadIdx.x; idx < total4;
         idx += stride) {
        const unsigned base = idx * 4u;                 // element index, %4==0
        const unsigned bi  = base >> 22;                // / (N*N), N*N = 2^22
        const unsigned rem = base & ((1u << 22) - 1u);
        const unsigned i   = rem >> 11;                 // / N
        const unsigned j   = rem & (N_ - 1u);
        const double si = s[bi * N_ + i];
        const double* sp = s + bi * N_ + j;             // 32B aligned (j%4==0)
        const double sj0 = sp[0], sj1 = sp[1], sj2 = sp[2], sj3 = sp[3];
        int4 o;
        o.x = (int)trunc((si - sj0) + b2);
        o.y = (int)trunc((si - sj1) + b2);
        o.z = (int)trunc((si - sj2) + b2);
        o.w = (int)trunc((si - sj3) + b2);
        *reinterpret_cast<int4*>(out + base) = o;
    }
}

extern "C" void kernel_launch(void* const* d_in, const int* in_sizes, int n_in,
                              void* d_out, int out_size, void* d_ws, size_t ws_size,
                              hipStream_t stream) {
    const float* hp = (const float*)d_in[0];
    // d_in[1] = node_mask (unused), d_in[2] = n_nodes (unused)
    const float* W1 = (const float*)d_in[3];
    const float* b1 = (const float*)d_in[4];
    const float* w2 = (const float*)d_in[5];
    const float* b2 = (const float*)d_in[6];

    float*  W1T = (float*)d_ws;                                   // 256 KB
    double* s   = (double*)((char*)d_ws + 256 * 1024);            // 128 KB
    int* out = (int*)d_out;

    transpose_w1<<<H_, H_, 0, stream>>>(W1, W1T);
    s_mfma_uni<<<(B_ * N_) / 32, 256, 0, stream>>>(hp, W1T, b1, w2, s);
    s_valu_kernel<<<(B_ * N_) / 16, 256, 0, stream>>>(hp, W1T, b1, w2, s);
    pair_kernel<<<2048, 256, 0, stream>>>(s, b2, out);
}